// Round 3
// baseline (9246.812 us; speedup 1.0000x reference)
//
#include <hip/hip_runtime.h>

// ---------------------------------------------------------------------------
// PerVarDecoder: 2-layer LSTM (D=512, B=512, L=256) on MI355X.
// R1: fence-free group barriers via relaxed agent-scope atomics (sc1 -> LLC).
// R2: padded barrier counters; OP partial stores (kill LLC line contention).
// R3 FAILED (absmax 0.25): 5 simultaneous changes, race not isolatable.
// R4 (this round): R2 base + ONE change: batch-issue all coherent A/y-operand
//   atomic loads into register arrays BEFORE the MFMA chain (one ~600cy LLC
//   RTT per GEMM instead of 32/64 serialized RTTs). Explicit vmcnt(0) drain
//   pins issue-all-then-wait ordering. Everything else identical to R2.
// ---------------------------------------------------------------------------

typedef __bf16 bf16_t;
typedef __bf16 bf16x8 __attribute__((ext_vector_type(8)));
typedef float f32x16 __attribute__((ext_vector_type(16)));

#define D_ 512
#define NB 256      // total blocks
#define TPB 256
#define SCOPE_DEV __HIP_MEMORY_SCOPE_AGENT

// ---- workspace layout (bytes) ----
#define OFF_O        0u                 // (unused this round, kept for layout stability)
#define OFF_CTR      524288u           // 16 groups x 64 u32 (256B stride) = 4096B
#define OFF_HL0      528384u           // 2 * 262144 bf16 = 1048576
#define OFF_HL1      1576960u          // 1048576
#define OFF_CL0      2625536u          // 262144 f32 = 1048576
#define OFF_CL1      3674112u          // 1048576
#define OFF_CSB      4722688u          // 262144 bf16 = 524288
#define OFF_IHWB     5246976u          // 524288 bf16 = 1048576
#define OFF_ICWB     6295552u          // 1048576
#define OFF_WHH0B    7344128u          // 1048576 bf16 = 2097152
#define OFF_WHH1B    9441280u          // 2097152
#define OFF_WIH1P    11538432u         // 2097152
#define OFF_GB0      13635584u         // 2048 f32 = 8192
#define OFF_GB1      13643776u         // 8192
#define OFF_Y0       13651968u         // 256*262144 bf16 = 134217728
#define OFF_OP       147869696u        // 16 * 131072 f32 = 8388608 (O partials per d-slice)
// total ~156 MB

__device__ __forceinline__ float sigm(float x) { return 1.0f / (1.0f + __expf(-x)); }
__device__ __forceinline__ float tanh_f(float x) { return 1.0f - 2.0f / (__expf(2.0f * x) + 1.0f); }

// 16B device-coherent load (2x 8B relaxed agent atomics -> sc1 bypass to LLC)
__device__ __forceinline__ bf16x8 ld16_dev(const bf16_t* p) {
    const unsigned long long* q = (const unsigned long long*)p;
    unsigned long long v0 = __hip_atomic_load(q, __ATOMIC_RELAXED, SCOPE_DEV);
    unsigned long long v1 = __hip_atomic_load(q + 1, __ATOMIC_RELAXED, SCOPE_DEV);
    union { unsigned long long u[2]; bf16x8 v; } c;
    c.u[0] = v0; c.u[1] = v1;
    return c.v;
}
// 8B device-coherent store (write-through to LLC)
__device__ __forceinline__ void st8_dev(bf16_t* p, unsigned long long v) {
    __hip_atomic_store((unsigned long long*)p, v, __ATOMIC_RELAXED, SCOPE_DEV);
}

// ---------------- prep: fp32->bf16 conversions + bias sums ----------------
__global__ void prep_kernel(const float* __restrict__ c_star, const float* __restrict__ ihw,
                            const float* __restrict__ icw, const float* __restrict__ whh0,
                            const float* __restrict__ whh1, const float* __restrict__ bi0,
                            const float* __restrict__ bh0, const float* __restrict__ bi1,
                            const float* __restrict__ bh1,
                            bf16_t* __restrict__ csb, bf16_t* __restrict__ ihwb,
                            bf16_t* __restrict__ icwb, bf16_t* __restrict__ whh0b,
                            bf16_t* __restrict__ whh1b, float* __restrict__ gb0,
                            float* __restrict__ gb1) {
    int id = blockIdx.x * TPB + threadIdx.x;
    if (id < 262144) { csb[id] = (bf16_t)c_star[id]; return; }
    id -= 262144;
    if (id < 524288) { ihwb[id] = (bf16_t)ihw[id]; return; }
    id -= 524288;
    if (id < 524288) { icwb[id] = (bf16_t)icw[id]; return; }
    id -= 524288;
    if (id < 1048576) { whh0b[id] = (bf16_t)whh0[id]; return; }
    id -= 1048576;
    if (id < 1048576) { whh1b[id] = (bf16_t)whh1[id]; return; }
    id -= 1048576;
    if (id < 2048) { gb0[id] = bi0[id] + bh0[id]; return; }
    id -= 2048;
    if (id < 2048) { gb1[id] = bi1[id] + bh1[id]; return; }
}

// ---------------- pack W_ih1 into MFMA B-fragment order ----------------
__global__ void pack_wih1_kernel(const float* __restrict__ W, bf16_t* __restrict__ out) {
    int id = blockIdx.x * TPB + threadIdx.x;  // 131072 chunks
    int j = id >> 13;
    int ch = id & 8191;
    int c = ch >> 6;             // 0..127 local col
    int k0 = (ch & 63) << 3;     // 0..511 step 8
    int q = c >> 5, dd = c & 31;
    int src = (q * 512 + j * 32 + dd) * 512 + k0;
    int kt = k0 >> 4, hi = (k0 >> 3) & 1;
    int off = (j * 4 + q) * 16384 + kt * 512 + ((hi << 5) + dd) * 8;
#pragma unroll
    for (int jj = 0; jj < 8; jj++) out[off + jj] = (bf16_t)W[src + jj];
}

// ---------------- init GEMM: h0/c0 = tanh(c_star @ W.T + b) ----------------
__global__ __launch_bounds__(TPB) void init_gemm_kernel(
    const bf16_t* __restrict__ csb, const bf16_t* __restrict__ ihwb,
    const bf16_t* __restrict__ icwb, const float* __restrict__ ihb,
    const float* __restrict__ icb, bf16_t* __restrict__ hl0, bf16_t* __restrict__ hl1,
    float* __restrict__ cl0, float* __restrict__ cl1) {
    int bid = blockIdx.x;
    int mt = bid & 15, nt = bid >> 4;
    int tid = threadIdx.x;
    int w = tid >> 6, l = tid & 63;
    int lane32 = l & 31, lhi = l >> 5;
    int m0 = mt * 32;
    int n0 = nt * 128 + w * 32;  // 0..2047
    bool is_h = (n0 < 1024);
    const bf16_t* Bmat = is_h ? ihwb : icwb;
    const float* bias = is_h ? ihb : icb;
    int nloc = is_h ? n0 : (n0 - 1024);

    f32x16 acc = {};
    const bf16_t* ap = csb + (m0 + lane32) * 512 + lhi * 8;
    const bf16_t* bp = Bmat + (nloc + lane32) * 512 + lhi * 8;
#pragma unroll
    for (int kt = 0; kt < 32; kt++) {
        bf16x8 a = *(const bf16x8*)(ap + kt * 16);
        bf16x8 b = *(const bf16x8*)(bp + kt * 16);
        acc = __builtin_amdgcn_mfma_f32_32x32x16_bf16(a, b, acc, 0, 0, 0);
    }
    int n = nloc + lane32;
    float bv = bias[n];
#pragma unroll
    for (int reg = 0; reg < 16; reg++) {
        int row = (reg & 3) + ((reg >> 2) << 3) + (lhi << 2);
        int m = m0 + row;
        float v = tanh_f(acc[reg] + bv);
        int flat = m * 1024 + n;  // reshape(NL,B,D) flat split semantics
        if (is_h) {
            if (flat < 262144) hl0[flat] = (bf16_t)v;
            else hl1[flat - 262144] = (bf16_t)v;
        } else {
            if (flat < 262144) cl0[flat] = v;
            else cl1[flat - 262144] = v;
        }
    }
}

// ---------------- main persistent cooperative LSTM kernel ----------------
__global__ __launch_bounds__(TPB, 1) void lstm_main_kernel(
    const bf16_t* __restrict__ whh0, const bf16_t* __restrict__ whh1,
    const bf16_t* __restrict__ wih1p, const float* __restrict__ gb0,
    const float* __restrict__ gb1, const float* __restrict__ out_w,
    bf16_t* __restrict__ hl0, bf16_t* __restrict__ hl1,
    const float* __restrict__ cl0i, const float* __restrict__ cl1i,
    bf16_t* __restrict__ y0, float* __restrict__ OP, unsigned* __restrict__ ctr) {
    __shared__ __align__(16) char smem[149504];  // 128KB W frags + 16KB gates + 2KB Hs
    bf16_t* Wlds = (bf16_t*)smem;
    float* G = (float*)(smem + 131072);
    bf16_t* Hs = (bf16_t*)(smem + 147456);  // 32 rows x 32 cols bf16

    const int bid = blockIdx.x;
    const int r8 = bid & 7, k8 = bid >> 3;
    const int g = r8 + ((k8 >> 4) << 3);  // group 0..15 (same-XCD hint)
    const int j = k8 & 15;                // d-slice within group
    const int b0 = g * 32, d0 = j * 32;
    const int tid = threadIdx.x;
    const int w = tid >> 6, l = tid & 63;
    const int lane32 = l & 31, lhi = l >> 5;
    const int ec = tid & 31, er = tid >> 5;  // elementwise (col, row-base)
    const int prow = tid >> 3, pc4 = (tid & 7) << 2;  // pack (row, col4)
    unsigned* myctr = ctr + g * 64;  // 256B stripe per group: no same-line contention

    // stage W_hh0 into frag-major LDS (input written by prior kernel: plain loads ok)
    for (int ch = tid; ch < 8192; ch += TPB) {
        int c = ch >> 6, k0 = (ch & 63) << 3;
        int q = c >> 5, dd = c & 31;
        bf16x8 v = *(const bf16x8*)(whh0 + (q * 512 + d0 + dd) * 512 + k0);
        *(bf16x8*)(Wlds + q * 16384 + (k0 >> 4) * 512 + ((((k0 >> 3) & 1) << 5) + dd) * 8) = v;
    }
    __syncthreads();

    float cst[4], bq[4];
#pragma unroll
    for (int p = 0; p < 4; p++) cst[p] = cl0i[(b0 + p * 8 + er) * 512 + d0 + ec];
#pragma unroll
    for (int q = 0; q < 4; q++) bq[q] = gb0[q * 512 + d0 + ec];

    int barcnt = 0;

    // ================= Phase A: layer 0 (input is bias-only) =================
    for (int t = 0; t < 256; t++) {
        const bf16_t* hcur = hl0 + (t & 1) * 262144;
        bf16_t* hnxt = hl0 + ((t + 1) & 1) * 262144;
        const bf16_t* ap = hcur + (b0 + lane32) * 512 + lhi * 8;
        const bf16_t* bp = Wlds + w * 16384 + l * 8;
        // batch-issue ALL coherent A loads first: one LLC RTT, not 32 serial
        bf16x8 ar[32];
#pragma unroll
        for (int kt = 0; kt < 32; kt++) ar[kt] = ld16_dev(ap + kt * 16);
        asm volatile("s_waitcnt vmcnt(0)" ::: "memory");
        f32x16 acc = {};
#pragma unroll
        for (int kt = 0; kt < 32; kt++) {
            bf16x8 b = *(const bf16x8*)(bp + kt * 512);
            acc = __builtin_amdgcn_mfma_f32_32x32x16_bf16(ar[kt], b, acc, 0, 0, 0);
        }
#pragma unroll
        for (int reg = 0; reg < 16; reg++) {
            int row = (reg & 3) + ((reg >> 2) << 3) + (lhi << 2);
            G[w * 1024 + row * 32 + lane32] = acc[reg];
        }
        __syncthreads();
#pragma unroll
        for (int p = 0; p < 4; p++) {
            int r = p * 8 + er;
            float iv = sigm(G[r * 32 + ec] + bq[0]);
            float fv = sigm(G[1024 + r * 32 + ec] + bq[1]);
            float gv = tanh_f(G[2048 + r * 32 + ec] + bq[2]);
            float ov = sigm(G[3072 + r * 32 + ec] + bq[3]);
            float cv = fv * cst[p] + iv * gv;
            cst[p] = cv;
            Hs[r * 32 + ec] = (bf16_t)(ov * tanh_f(cv));
        }
        __syncthreads();
        // pack 8B chunks, write-through to LLC (h for siblings, y0 for phase B)
        {
            unsigned long long v = *(const unsigned long long*)(Hs + prow * 32 + pc4);
            int gi = (b0 + prow) * 512 + d0 + pc4;
            st8_dev(hnxt + gi, v);
            st8_dev(y0 + t * 262144 + gi, v);
        }
        asm volatile("s_waitcnt vmcnt(0)" ::: "memory");
        __syncthreads();
        barcnt++;
        if (tid == 0) {
            __hip_atomic_fetch_add(myctr, 1u, __ATOMIC_RELAXED, SCOPE_DEV);
            unsigned tgt = (unsigned)(16 * barcnt);
            while (__hip_atomic_load(myctr, __ATOMIC_RELAXED, SCOPE_DEV) < tgt)
                __builtin_amdgcn_s_sleep(2);
        }
        __syncthreads();
    }

    // stage W_hh1 (all waves past GEMM reads due to final barrier)
    for (int ch = tid; ch < 8192; ch += TPB) {
        int c = ch >> 6, k0 = (ch & 63) << 3;
        int q = c >> 5, dd = c & 31;
        bf16x8 v = *(const bf16x8*)(whh1 + (q * 512 + d0 + dd) * 512 + k0);
        *(bf16x8*)(Wlds + q * 16384 + (k0 >> 4) * 512 + ((((k0 >> 3) & 1) << 5) + dd) * 8) = v;
    }
    __syncthreads();
#pragma unroll
    for (int p = 0; p < 4; p++) cst[p] = cl1i[(b0 + p * 8 + er) * 512 + d0 + ec];
#pragma unroll
    for (int q = 0; q < 4; q++) bq[q] = gb1[q * 512 + d0 + ec];
    const float ow = out_w[d0 + ec];
    const bf16_t* wp = wih1p + (j * 4 + w) * 16384 + l * 8;
    float* opj = OP + j * 131072;  // this block's private O-partial slice

    // ================= Phase B: layer 1 (K=1024 fused) + out proj ============
    for (int t = 0; t < 256; t++) {
        const bf16_t* hcur = hl1 + (t & 1) * 262144;
        bf16_t* hnxt = hl1 + ((t + 1) & 1) * 262144;
        f32x16 acc = {};
        // y-GEMM: batch loads, one RTT
        {
            const bf16_t* yp = y0 + t * 262144 + (b0 + lane32) * 512 + lhi * 8;
            bf16x8 yr[32];
#pragma unroll
            for (int kt = 0; kt < 32; kt++) yr[kt] = ld16_dev(yp + kt * 16);
            asm volatile("s_waitcnt vmcnt(0)" ::: "memory");
#pragma unroll
            for (int kt = 0; kt < 32; kt++)
                acc = __builtin_amdgcn_mfma_f32_32x32x16_bf16(yr[kt], *(const bf16x8*)(wp + kt * 512), acc, 0, 0, 0);
        }
        // h-GEMM: batch loads, one RTT
        {
            const bf16_t* ap = hcur + (b0 + lane32) * 512 + lhi * 8;
            const bf16_t* bp = Wlds + w * 16384 + l * 8;
            bf16x8 ar[32];
#pragma unroll
            for (int kt = 0; kt < 32; kt++) ar[kt] = ld16_dev(ap + kt * 16);
            asm volatile("s_waitcnt vmcnt(0)" ::: "memory");
#pragma unroll
            for (int kt = 0; kt < 32; kt++) {
                bf16x8 b = *(const bf16x8*)(bp + kt * 512);
                acc = __builtin_amdgcn_mfma_f32_32x32x16_bf16(ar[kt], b, acc, 0, 0, 0);
            }
        }
#pragma unroll
        for (int reg = 0; reg < 16; reg++) {
            int row = (reg & 3) + ((reg >> 2) << 3) + (lhi << 2);
            G[w * 1024 + row * 32 + lane32] = acc[reg];
        }
        __syncthreads();
#pragma unroll
        for (int p = 0; p < 4; p++) {
            int r = p * 8 + er;
            float iv = sigm(G[r * 32 + ec] + bq[0]);
            float fv = sigm(G[1024 + r * 32 + ec] + bq[1]);
            float gv = tanh_f(G[2048 + r * 32 + ec] + bq[2]);
            float ov = sigm(G[3072 + r * 32 + ec] + bq[3]);
            float cv = fv * cst[p] + iv * gv;
            cst[p] = cv;
            float hv = ov * tanh_f(cv);
            Hs[r * 32 + ec] = (bf16_t)hv;
            float part = hv * ow;
#pragma unroll
            for (int off = 16; off; off >>= 1) part += __shfl_xor(part, off, 32);
            if (ec == 0) opj[t * 512 + b0 + r] = part;  // contention-free partial
        }
        __syncthreads();
        {
            unsigned long long v = *(const unsigned long long*)(Hs + prow * 32 + pc4);
            st8_dev(hnxt + (b0 + prow) * 512 + d0 + pc4, v);
        }
        asm volatile("s_waitcnt vmcnt(0)" ::: "memory");
        __syncthreads();
        barcnt++;
        if (tid == 0) {
            __hip_atomic_fetch_add(myctr, 1u, __ATOMIC_RELAXED, SCOPE_DEV);
            unsigned tgt = (unsigned)(16 * barcnt);
            while (__hip_atomic_load(myctr, __ATOMIC_RELAXED, SCOPE_DEV) < tgt)
                __builtin_amdgcn_s_sleep(2);
        }
        __syncthreads();
    }
}

// ------------- finalize: 16-way O-partial reduce + out_b + reorder -------------
__global__ void finalize_kernel(const float* __restrict__ OP, const float* __restrict__ out_b,
                                float* __restrict__ out) {
    int id = blockIdx.x * TPB + threadIdx.x;  // 131072
    int t = id >> 9, b = id & 511;
    float v = out_b[0];
#pragma unroll
    for (int jj = 0; jj < 16; jj++) v += OP[jj * 131072 + id];
    if (t < 255) out[b * 255 + t] = v;
    else out[130560 + b] = v;
}

extern "C" void kernel_launch(void* const* d_in, const int* in_sizes, int n_in,
                              void* d_out, int out_size, void* d_ws, size_t ws_size,
                              hipStream_t stream) {
    const float* c_star = (const float*)d_in[0];
    const float* init_h_w = (const float*)d_in[1];
    const float* init_h_b = (const float*)d_in[2];
    const float* init_c_w = (const float*)d_in[3];
    const float* init_c_b = (const float*)d_in[4];
    // d_in[5] = W_ih0 (unused by reference)
    const float* W_hh0 = (const float*)d_in[6];
    const float* b_ih0 = (const float*)d_in[7];
    const float* b_hh0 = (const float*)d_in[8];
    const float* W_ih1 = (const float*)d_in[9];
    const float* W_hh1 = (const float*)d_in[10];
    const float* b_ih1 = (const float*)d_in[11];
    const float* b_hh1 = (const float*)d_in[12];
    const float* out_w = (const float*)d_in[13];
    const float* out_b = (const float*)d_in[14];

    char* ws = (char*)d_ws;
    unsigned* ctr = (unsigned*)(ws + OFF_CTR);
    bf16_t* hl0 = (bf16_t*)(ws + OFF_HL0);
    bf16_t* hl1 = (bf16_t*)(ws + OFF_HL1);
    float* cl0 = (float*)(ws + OFF_CL0);
    float* cl1 = (float*)(ws + OFF_CL1);
    bf16_t* csb = (bf16_t*)(ws + OFF_CSB);
    bf16_t* ihwb = (bf16_t*)(ws + OFF_IHWB);
    bf16_t* icwb = (bf16_t*)(ws + OFF_ICWB);
    bf16_t* whh0b = (bf16_t*)(ws + OFF_WHH0B);
    bf16_t* whh1b = (bf16_t*)(ws + OFF_WHH1B);
    bf16_t* wih1p = (bf16_t*)(ws + OFF_WIH1P);
    float* gb0 = (float*)(ws + OFF_GB0);
    float* gb1 = (float*)(ws + OFF_GB1);
    bf16_t* y0 = (bf16_t*)(ws + OFF_Y0);
    float* OP = (float*)(ws + OFF_OP);

    // zero group barrier counters (ws is poisoned each call); OP is fully
    // overwritten in Phase B before finalize reads it -> no zeroing needed
    hipMemsetAsync(ws + OFF_CTR, 0, 4096, stream);

    prep_kernel<<<13328, TPB, 0, stream>>>(c_star, init_h_w, init_c_w, W_hh0, W_hh1,
                                           b_ih0, b_hh0, b_ih1, b_hh1,
                                           csb, ihwb, icwb, whh0b, whh1b, gb0, gb1);
    pack_wih1_kernel<<<512, TPB, 0, stream>>>(W_ih1, wih1p);
    init_gemm_kernel<<<256, TPB, 0, stream>>>(csb, ihwb, icwb, init_h_b, init_c_b,
                                              hl0, hl1, cl0, cl1);

    const bf16_t* a_whh0 = whh0b; const bf16_t* a_whh1 = whh1b;
    const bf16_t* a_wih1p = wih1p; const float* a_gb0 = gb0; const float* a_gb1 = gb1;
    const float* a_outw = out_w;
    bf16_t* a_hl0 = hl0; bf16_t* a_hl1 = hl1;
    const float* a_cl0 = cl0; const float* a_cl1 = cl1;
    bf16_t* a_y0 = y0; float* a_OP = OP; unsigned* a_ctr = ctr;
    void* args[] = {&a_whh0, &a_whh1, &a_wih1p, &a_gb0, &a_gb1, &a_outw,
                    &a_hl0, &a_hl1, &a_cl0, &a_cl1, &a_y0, &a_OP, &a_ctr};
    hipLaunchCooperativeKernel((void*)lstm_main_kernel, dim3(NB), dim3(TPB), args, 0, stream);

    finalize_kernel<<<512, TPB, 0, stream>>>(OP, out_b, (float*)d_out);
}

// Round 6
// 9238.552 us; speedup vs baseline: 1.0009x; 1.0009x over previous
//
#include <hip/hip_runtime.h>

// ---------------------------------------------------------------------------
// PerVarDecoder: 2-layer LSTM (D=512, B=512, L=256) on MI355X.
// R1: fence-free group barriers via relaxed agent-scope atomics (sc1 -> LLC).
// R2: padded barrier counters; OP partial stores (kill LLC line contention).
// R3 FAILED (0.2495): batch + compiler COUNTED vmcnt(N) waits.
// R4 NEUTRAL: batch + vmcnt(0) asm, but scheduler re-interleaved (VGPR 132).
// R5 FAILED (0.2495 == R3): sched_barrier pinned the batch, but consumes used
//   compiler counted vmcnt(N). Diagnosis: coherent sc1 loads return OUT OF
//   ORDER across LLC channels -> counted waits release consumers early.
// R6: batch all loads -> sched_barrier(0) -> s_waitcnt vmcnt(0)
//   -> sched_barrier(0) -> MFMAs. Full drain (one RTT for 64 in-flight loads),
//   NO counted waits, MFMAs pinned below the drain (rule #18 both sides).
//   INFRA FAILURE (container died twice) -- no data.
// R7 (this round): identical resubmit of R6 (theory untested; do not confound).
// ---------------------------------------------------------------------------

typedef __bf16 bf16_t;
typedef __bf16 bf16x8 __attribute__((ext_vector_type(8)));
typedef float f32x16 __attribute__((ext_vector_type(16)));

#define D_ 512
#define NB 256      // total blocks
#define TPB 256
#define SCOPE_DEV __HIP_MEMORY_SCOPE_AGENT

// ---- workspace layout (bytes) ----
#define OFF_O        0u                 // (unused this round, kept for layout stability)
#define OFF_CTR      524288u           // 16 groups x 64 u32 (256B stride) = 4096B
#define OFF_HL0      528384u           // 2 * 262144 bf16 = 1048576
#define OFF_HL1      1576960u          // 1048576
#define OFF_CL0      2625536u          // 262144 f32 = 1048576
#define OFF_CL1      3674112u          // 1048576
#define OFF_CSB      4722688u          // 262144 bf16 = 524288
#define OFF_IHWB     5246976u          // 524288 bf16 = 1048576
#define OFF_ICWB     6295552u          // 1048576
#define OFF_WHH0B    7344128u          // 1048576 bf16 = 2097152
#define OFF_WHH1B    9441280u          // 2097152
#define OFF_WIH1P    11538432u         // 2097152
#define OFF_GB0      13635584u         // 2048 f32 = 8192
#define OFF_GB1      13643776u         // 8192
#define OFF_Y0       13651968u         // 256*262144 bf16 = 134217728
#define OFF_OP       147869696u        // 16 * 131072 f32 = 8388608 (O partials per d-slice)
// total ~156 MB

__device__ __forceinline__ float sigm(float x) { return 1.0f / (1.0f + __expf(-x)); }
__device__ __forceinline__ float tanh_f(float x) { return 1.0f - 2.0f / (__expf(2.0f * x) + 1.0f); }

// 16B device-coherent load (2x 8B relaxed agent atomics -> sc1 bypass to LLC)
__device__ __forceinline__ bf16x8 ld16_dev(const bf16_t* p) {
    const unsigned long long* q = (const unsigned long long*)p;
    unsigned long long v0 = __hip_atomic_load(q, __ATOMIC_RELAXED, SCOPE_DEV);
    unsigned long long v1 = __hip_atomic_load(q + 1, __ATOMIC_RELAXED, SCOPE_DEV);
    union { unsigned long long u[2]; bf16x8 v; } c;
    c.u[0] = v0; c.u[1] = v1;
    return c.v;
}
// 8B device-coherent store (write-through to LLC)
__device__ __forceinline__ void st8_dev(bf16_t* p, unsigned long long v) {
    __hip_atomic_store((unsigned long long*)p, v, __ATOMIC_RELAXED, SCOPE_DEV);
}

// ---------------- prep: fp32->bf16 conversions + bias sums ----------------
__global__ void prep_kernel(const float* __restrict__ c_star, const float* __restrict__ ihw,
                            const float* __restrict__ icw, const float* __restrict__ whh0,
                            const float* __restrict__ whh1, const float* __restrict__ bi0,
                            const float* __restrict__ bh0, const float* __restrict__ bi1,
                            const float* __restrict__ bh1,
                            bf16_t* __restrict__ csb, bf16_t* __restrict__ ihwb,
                            bf16_t* __restrict__ icwb, bf16_t* __restrict__ whh0b,
                            bf16_t* __restrict__ whh1b, float* __restrict__ gb0,
                            float* __restrict__ gb1) {
    int id = blockIdx.x * TPB + threadIdx.x;
    if (id < 262144) { csb[id] = (bf16_t)c_star[id]; return; }
    id -= 262144;
    if (id < 524288) { ihwb[id] = (bf16_t)ihw[id]; return; }
    id -= 524288;
    if (id < 524288) { icwb[id] = (bf16_t)icw[id]; return; }
    id -= 524288;
    if (id < 1048576) { whh0b[id] = (bf16_t)whh0[id]; return; }
    id -= 1048576;
    if (id < 1048576) { whh1b[id] = (bf16_t)whh1[id]; return; }
    id -= 1048576;
    if (id < 2048) { gb0[id] = bi0[id] + bh0[id]; return; }
    id -= 2048;
    if (id < 2048) { gb1[id] = bi1[id] + bh1[id]; return; }
}

// ---------------- pack W_ih1 into MFMA B-fragment order ----------------
__global__ void pack_wih1_kernel(const float* __restrict__ W, bf16_t* __restrict__ out) {
    int id = blockIdx.x * TPB + threadIdx.x;  // 131072 chunks
    int j = id >> 13;
    int ch = id & 8191;
    int c = ch >> 6;             // 0..127 local col
    int k0 = (ch & 63) << 3;     // 0..511 step 8
    int q = c >> 5, dd = c & 31;
    int src = (q * 512 + j * 32 + dd) * 512 + k0;
    int kt = k0 >> 4, hi = (k0 >> 3) & 1;
    int off = (j * 4 + q) * 16384 + kt * 512 + ((hi << 5) + dd) * 8;
#pragma unroll
    for (int jj = 0; jj < 8; jj++) out[off + jj] = (bf16_t)W[src + jj];
}

// ---------------- init GEMM: h0/c0 = tanh(c_star @ W.T + b) ----------------
__global__ __launch_bounds__(TPB) void init_gemm_kernel(
    const bf16_t* __restrict__ csb, const bf16_t* __restrict__ ihwb,
    const bf16_t* __restrict__ icwb, const float* __restrict__ ihb,
    const float* __restrict__ icb, bf16_t* __restrict__ hl0, bf16_t* __restrict__ hl1,
    float* __restrict__ cl0, float* __restrict__ cl1) {
    int bid = blockIdx.x;
    int mt = bid & 15, nt = bid >> 4;
    int tid = threadIdx.x;
    int w = tid >> 6, l = tid & 63;
    int lane32 = l & 31, lhi = l >> 5;
    int m0 = mt * 32;
    int n0 = nt * 128 + w * 32;  // 0..2047
    bool is_h = (n0 < 1024);
    const bf16_t* Bmat = is_h ? ihwb : icwb;
    const float* bias = is_h ? ihb : icb;
    int nloc = is_h ? n0 : (n0 - 1024);

    f32x16 acc = {};
    const bf16_t* ap = csb + (m0 + lane32) * 512 + lhi * 8;
    const bf16_t* bp = Bmat + (nloc + lane32) * 512 + lhi * 8;
#pragma unroll
    for (int kt = 0; kt < 32; kt++) {
        bf16x8 a = *(const bf16x8*)(ap + kt * 16);
        bf16x8 b = *(const bf16x8*)(bp + kt * 16);
        acc = __builtin_amdgcn_mfma_f32_32x32x16_bf16(a, b, acc, 0, 0, 0);
    }
    int n = nloc + lane32;
    float bv = bias[n];
#pragma unroll
    for (int reg = 0; reg < 16; reg++) {
        int row = (reg & 3) + ((reg >> 2) << 3) + (lhi << 2);
        int m = m0 + row;
        float v = tanh_f(acc[reg] + bv);
        int flat = m * 1024 + n;  // reshape(NL,B,D) flat split semantics
        if (is_h) {
            if (flat < 262144) hl0[flat] = (bf16_t)v;
            else hl1[flat - 262144] = (bf16_t)v;
        } else {
            if (flat < 262144) cl0[flat] = v;
            else cl1[flat - 262144] = v;
        }
    }
}

// ---------------- main persistent cooperative LSTM kernel ----------------
__global__ __launch_bounds__(TPB, 1) void lstm_main_kernel(
    const bf16_t* __restrict__ whh0, const bf16_t* __restrict__ whh1,
    const bf16_t* __restrict__ wih1p, const float* __restrict__ gb0,
    const float* __restrict__ gb1, const float* __restrict__ out_w,
    bf16_t* __restrict__ hl0, bf16_t* __restrict__ hl1,
    const float* __restrict__ cl0i, const float* __restrict__ cl1i,
    bf16_t* __restrict__ y0, float* __restrict__ OP, unsigned* __restrict__ ctr) {
    __shared__ __align__(16) char smem[149504];  // 128KB W frags + 16KB gates + 2KB Hs
    bf16_t* Wlds = (bf16_t*)smem;
    float* G = (float*)(smem + 131072);
    bf16_t* Hs = (bf16_t*)(smem + 147456);  // 32 rows x 32 cols bf16

    const int bid = blockIdx.x;
    const int r8 = bid & 7, k8 = bid >> 3;
    const int g = r8 + ((k8 >> 4) << 3);  // group 0..15 (same-XCD hint)
    const int j = k8 & 15;                // d-slice within group
    const int b0 = g * 32, d0 = j * 32;
    const int tid = threadIdx.x;
    const int w = tid >> 6, l = tid & 63;
    const int lane32 = l & 31, lhi = l >> 5;
    const int ec = tid & 31, er = tid >> 5;  // elementwise (col, row-base)
    const int prow = tid >> 3, pc4 = (tid & 7) << 2;  // pack (row, col4)
    unsigned* myctr = ctr + g * 64;  // 256B stripe per group: no same-line contention

    // stage W_hh0 into frag-major LDS (input written by prior kernel: plain loads ok)
    for (int ch = tid; ch < 8192; ch += TPB) {
        int c = ch >> 6, k0 = (ch & 63) << 3;
        int q = c >> 5, dd = c & 31;
        bf16x8 v = *(const bf16x8*)(whh0 + (q * 512 + d0 + dd) * 512 + k0);
        *(bf16x8*)(Wlds + q * 16384 + (k0 >> 4) * 512 + ((((k0 >> 3) & 1) << 5) + dd) * 8) = v;
    }
    __syncthreads();

    float cst[4], bq[4];
#pragma unroll
    for (int p = 0; p < 4; p++) cst[p] = cl0i[(b0 + p * 8 + er) * 512 + d0 + ec];
#pragma unroll
    for (int q = 0; q < 4; q++) bq[q] = gb0[q * 512 + d0 + ec];

    int barcnt = 0;

    // ================= Phase A: layer 0 (input is bias-only) =================
    for (int t = 0; t < 256; t++) {
        const bf16_t* hcur = hl0 + (t & 1) * 262144;
        bf16_t* hnxt = hl0 + ((t + 1) & 1) * 262144;
        const bf16_t* ap = hcur + (b0 + lane32) * 512 + lhi * 8;
        const bf16_t* bp = Wlds + w * 16384 + l * 8;
        // batch-issue ALL coherent A loads (one LLC RTT), then FULL drain.
        // sched_barrier both sides: loads can't sink, MFMAs can't hoist past
        // the asm wait (rule #18). No counted vmcnt anywhere (OOO returns).
        bf16x8 ar[32];
#pragma unroll
        for (int kt = 0; kt < 32; kt++) ar[kt] = ld16_dev(ap + kt * 16);
        __builtin_amdgcn_sched_barrier(0);
        asm volatile("s_waitcnt vmcnt(0)" ::: "memory");
        __builtin_amdgcn_sched_barrier(0);
        f32x16 acc = {};
#pragma unroll
        for (int kt = 0; kt < 32; kt++) {
            bf16x8 b = *(const bf16x8*)(bp + kt * 512);
            acc = __builtin_amdgcn_mfma_f32_32x32x16_bf16(ar[kt], b, acc, 0, 0, 0);
        }
#pragma unroll
        for (int reg = 0; reg < 16; reg++) {
            int row = (reg & 3) + ((reg >> 2) << 3) + (lhi << 2);
            G[w * 1024 + row * 32 + lane32] = acc[reg];
        }
        __syncthreads();
#pragma unroll
        for (int p = 0; p < 4; p++) {
            int r = p * 8 + er;
            float iv = sigm(G[r * 32 + ec] + bq[0]);
            float fv = sigm(G[1024 + r * 32 + ec] + bq[1]);
            float gv = tanh_f(G[2048 + r * 32 + ec] + bq[2]);
            float ov = sigm(G[3072 + r * 32 + ec] + bq[3]);
            float cv = fv * cst[p] + iv * gv;
            cst[p] = cv;
            Hs[r * 32 + ec] = (bf16_t)(ov * tanh_f(cv));
        }
        __syncthreads();
        // pack 8B chunks, write-through to LLC (h for siblings, y0 for phase B)
        {
            unsigned long long v = *(const unsigned long long*)(Hs + prow * 32 + pc4);
            int gi = (b0 + prow) * 512 + d0 + pc4;
            st8_dev(hnxt + gi, v);
            st8_dev(y0 + t * 262144 + gi, v);
        }
        asm volatile("s_waitcnt vmcnt(0)" ::: "memory");
        __syncthreads();
        barcnt++;
        if (tid == 0) {
            __hip_atomic_fetch_add(myctr, 1u, __ATOMIC_RELAXED, SCOPE_DEV);
            unsigned tgt = (unsigned)(16 * barcnt);
            while (__hip_atomic_load(myctr, __ATOMIC_RELAXED, SCOPE_DEV) < tgt)
                __builtin_amdgcn_s_sleep(2);
        }
        __syncthreads();
    }

    // stage W_hh1 (all waves past GEMM reads due to final barrier)
    for (int ch = tid; ch < 8192; ch += TPB) {
        int c = ch >> 6, k0 = (ch & 63) << 3;
        int q = c >> 5, dd = c & 31;
        bf16x8 v = *(const bf16x8*)(whh1 + (q * 512 + d0 + dd) * 512 + k0);
        *(bf16x8*)(Wlds + q * 16384 + (k0 >> 4) * 512 + ((((k0 >> 3) & 1) << 5) + dd) * 8) = v;
    }
    __syncthreads();
#pragma unroll
    for (int p = 0; p < 4; p++) cst[p] = cl1i[(b0 + p * 8 + er) * 512 + d0 + ec];
#pragma unroll
    for (int q = 0; q < 4; q++) bq[q] = gb1[q * 512 + d0 + ec];
    const float ow = out_w[d0 + ec];
    const bf16_t* wp = wih1p + (j * 4 + w) * 16384 + l * 8;
    float* opj = OP + j * 131072;  // this block's private O-partial slice

    // ================= Phase B: layer 1 (K=1024 fused) + out proj ============
    for (int t = 0; t < 256; t++) {
        const bf16_t* hcur = hl1 + (t & 1) * 262144;
        bf16_t* hnxt = hl1 + ((t + 1) & 1) * 262144;
        f32x16 acc = {};
        // y-GEMM: batch loads, full drain, pinned both sides
        {
            const bf16_t* yp = y0 + t * 262144 + (b0 + lane32) * 512 + lhi * 8;
            bf16x8 yr[32];
#pragma unroll
            for (int kt = 0; kt < 32; kt++) yr[kt] = ld16_dev(yp + kt * 16);
            __builtin_amdgcn_sched_barrier(0);
            asm volatile("s_waitcnt vmcnt(0)" ::: "memory");
            __builtin_amdgcn_sched_barrier(0);
#pragma unroll
            for (int kt = 0; kt < 32; kt++)
                acc = __builtin_amdgcn_mfma_f32_32x32x16_bf16(yr[kt], *(const bf16x8*)(wp + kt * 512), acc, 0, 0, 0);
        }
        // h-GEMM: batch loads, full drain, pinned both sides
        {
            const bf16_t* ap = hcur + (b0 + lane32) * 512 + lhi * 8;
            const bf16_t* bp = Wlds + w * 16384 + l * 8;
            bf16x8 ar[32];
#pragma unroll
            for (int kt = 0; kt < 32; kt++) ar[kt] = ld16_dev(ap + kt * 16);
            __builtin_amdgcn_sched_barrier(0);
            asm volatile("s_waitcnt vmcnt(0)" ::: "memory");
            __builtin_amdgcn_sched_barrier(0);
#pragma unroll
            for (int kt = 0; kt < 32; kt++) {
                bf16x8 b = *(const bf16x8*)(bp + kt * 512);
                acc = __builtin_amdgcn_mfma_f32_32x32x16_bf16(ar[kt], b, acc, 0, 0, 0);
            }
        }
#pragma unroll
        for (int reg = 0; reg < 16; reg++) {
            int row = (reg & 3) + ((reg >> 2) << 3) + (lhi << 2);
            G[w * 1024 + row * 32 + lane32] = acc[reg];
        }
        __syncthreads();
#pragma unroll
        for (int p = 0; p < 4; p++) {
            int r = p * 8 + er;
            float iv = sigm(G[r * 32 + ec] + bq[0]);
            float fv = sigm(G[1024 + r * 32 + ec] + bq[1]);
            float gv = tanh_f(G[2048 + r * 32 + ec] + bq[2]);
            float ov = sigm(G[3072 + r * 32 + ec] + bq[3]);
            float cv = fv * cst[p] + iv * gv;
            cst[p] = cv;
            float hv = ov * tanh_f(cv);
            Hs[r * 32 + ec] = (bf16_t)hv;
            float part = hv * ow;
#pragma unroll
            for (int off = 16; off; off >>= 1) part += __shfl_xor(part, off, 32);
            if (ec == 0) opj[t * 512 + b0 + r] = part;  // contention-free partial
        }
        __syncthreads();
        {
            unsigned long long v = *(const unsigned long long*)(Hs + prow * 32 + pc4);
            st8_dev(hnxt + (b0 + prow) * 512 + d0 + pc4, v);
        }
        asm volatile("s_waitcnt vmcnt(0)" ::: "memory");
        __syncthreads();
        barcnt++;
        if (tid == 0) {
            __hip_atomic_fetch_add(myctr, 1u, __ATOMIC_RELAXED, SCOPE_DEV);
            unsigned tgt = (unsigned)(16 * barcnt);
            while (__hip_atomic_load(myctr, __ATOMIC_RELAXED, SCOPE_DEV) < tgt)
                __builtin_amdgcn_s_sleep(2);
        }
        __syncthreads();
    }
}

// ------------- finalize: 16-way O-partial reduce + out_b + reorder -------------
__global__ void finalize_kernel(const float* __restrict__ OP, const float* __restrict__ out_b,
                                float* __restrict__ out) {
    int id = blockIdx.x * TPB + threadIdx.x;  // 131072
    int t = id >> 9, b = id & 511;
    float v = out_b[0];
#pragma unroll
    for (int jj = 0; jj < 16; jj++) v += OP[jj * 131072 + id];
    if (t < 255) out[b * 255 + t] = v;
    else out[130560 + b] = v;
}

extern "C" void kernel_launch(void* const* d_in, const int* in_sizes, int n_in,
                              void* d_out, int out_size, void* d_ws, size_t ws_size,
                              hipStream_t stream) {
    const float* c_star = (const float*)d_in[0];
    const float* init_h_w = (const float*)d_in[1];
    const float* init_h_b = (const float*)d_in[2];
    const float* init_c_w = (const float*)d_in[3];
    const float* init_c_b = (const float*)d_in[4];
    // d_in[5] = W_ih0 (unused by reference)
    const float* W_hh0 = (const float*)d_in[6];
    const float* b_ih0 = (const float*)d_in[7];
    const float* b_hh0 = (const float*)d_in[8];
    const float* W_ih1 = (const float*)d_in[9];
    const float* W_hh1 = (const float*)d_in[10];
    const float* b_ih1 = (const float*)d_in[11];
    const float* b_hh1 = (const float*)d_in[12];
    const float* out_w = (const float*)d_in[13];
    const float* out_b = (const float*)d_in[14];

    char* ws = (char*)d_ws;
    unsigned* ctr = (unsigned*)(ws + OFF_CTR);
    bf16_t* hl0 = (bf16_t*)(ws + OFF_HL0);
    bf16_t* hl1 = (bf16_t*)(ws + OFF_HL1);
    float* cl0 = (float*)(ws + OFF_CL0);
    float* cl1 = (float*)(ws + OFF_CL1);
    bf16_t* csb = (bf16_t*)(ws + OFF_CSB);
    bf16_t* ihwb = (bf16_t*)(ws + OFF_IHWB);
    bf16_t* icwb = (bf16_t*)(ws + OFF_ICWB);
    bf16_t* whh0b = (bf16_t*)(ws + OFF_WHH0B);
    bf16_t* whh1b = (bf16_t*)(ws + OFF_WHH1B);
    bf16_t* wih1p = (bf16_t*)(ws + OFF_WIH1P);
    float* gb0 = (float*)(ws + OFF_GB0);
    float* gb1 = (float*)(ws + OFF_GB1);
    bf16_t* y0 = (bf16_t*)(ws + OFF_Y0);
    float* OP = (float*)(ws + OFF_OP);

    // zero group barrier counters (ws is poisoned each call); OP is fully
    // overwritten in Phase B before finalize reads it -> no zeroing needed
    hipMemsetAsync(ws + OFF_CTR, 0, 4096, stream);

    prep_kernel<<<13328, TPB, 0, stream>>>(c_star, init_h_w, init_c_w, W_hh0, W_hh1,
                                           b_ih0, b_hh0, b_ih1, b_hh1,
                                           csb, ihwb, icwb, whh0b, whh1b, gb0, gb1);
    pack_wih1_kernel<<<512, TPB, 0, stream>>>(W_ih1, wih1p);
    init_gemm_kernel<<<256, TPB, 0, stream>>>(csb, ihwb, icwb, init_h_b, init_c_b,
                                              hl0, hl1, cl0, cl1);

    const bf16_t* a_whh0 = whh0b; const bf16_t* a_whh1 = whh1b;
    const bf16_t* a_wih1p = wih1p; const float* a_gb0 = gb0; const float* a_gb1 = gb1;
    const float* a_outw = out_w;
    bf16_t* a_hl0 = hl0; bf16_t* a_hl1 = hl1;
    const float* a_cl0 = cl0; const float* a_cl1 = cl1;
    bf16_t* a_y0 = y0; float* a_OP = OP; unsigned* a_ctr = ctr;
    void* args[] = {&a_whh0, &a_whh1, &a_wih1p, &a_gb0, &a_gb1, &a_outw,
                    &a_hl0, &a_hl1, &a_cl0, &a_cl1, &a_y0, &a_OP, &a_ctr};
    hipLaunchCooperativeKernel((void*)lstm_main_kernel, dim3(NB), dim3(TPB), args, 0, stream);

    finalize_kernel<<<512, TPB, 0, stream>>>(OP, out_b, (float*)d_out);
}

// Round 8
// 7342.110 us; speedup vs baseline: 1.2594x; 1.2583x over previous
//
#include <hip/hip_runtime.h>

// ---------------------------------------------------------------------------
// PerVarDecoder: 2-layer LSTM (D=512, B=512, L=256) on MI355X.
// R1: fence-free group barriers via relaxed agent-scope atomics (sc1 -> LLC).
// R2: padded barrier counters; OP partial stores (kill LLC line contention). 7982us.
// R3/R5/R8 FAILED (absmax 0.2495 each): three attempts to batch the coherent
//   h-loads (HIP atomics, sched_barrier-pinned, inline asm + full drain) all
//   perturb the h-stream; mechanism unresolved. Burst-loading the COHERENT
//   path is abandoned.
// R9 (this round): exploit the one GEMM that needs NO coherence: y0[t] is
//   written once in Phase A (drained before group barriers) and first READ in
//   Phase B (L2 invalidated at dispatch -> no stale copy possible). So the
//   y-GEMM uses PLAIN CACHED loads -- unordered, compiler pipelines them
//   natively (standard GEMM codegen), counted waits are safe. Removes half of
//   Phase B's serialized ~600cy LLC round trips. h-path stays ld16_dev
//   (proven correct; sc-stores don't invalidate reader L2 copies, so h MUST
//   bypass caches). Everything else byte-identical to R2.
// ---------------------------------------------------------------------------

typedef __bf16 bf16_t;
typedef __bf16 bf16x8 __attribute__((ext_vector_type(8)));
typedef float f32x16 __attribute__((ext_vector_type(16)));

#define D_ 512
#define NB 256      // total blocks
#define TPB 256
#define SCOPE_DEV __HIP_MEMORY_SCOPE_AGENT

// ---- workspace layout (bytes) ----
#define OFF_O        0u                 // (unused, layout stability)
#define OFF_CTR      524288u           // 16 groups x 64 u32 (256B stride) = 4096B
#define OFF_HL0      528384u           // 2 * 262144 bf16 = 1048576
#define OFF_HL1      1576960u          // 1048576
#define OFF_CL0      2625536u          // 262144 f32 = 1048576
#define OFF_CL1      3674112u          // 1048576
#define OFF_CSB      4722688u          // 262144 bf16 = 524288
#define OFF_IHWB     5246976u          // 524288 bf16 = 1048576
#define OFF_ICWB     6295552u          // 1048576
#define OFF_WHH0B    7344128u          // 1048576 bf16 = 2097152
#define OFF_WHH1B    9441280u          // 2097152
#define OFF_WIH1P    11538432u         // 2097152
#define OFF_GB0      13635584u         // 2048 f32 = 8192
#define OFF_GB1      13643776u         // 8192
#define OFF_Y0       13651968u         // 256*262144 bf16 = 134217728
#define OFF_OP       147869696u        // 16 * 131072 f32 = 8388608
// total ~156 MB

__device__ __forceinline__ float sigm(float x) { return 1.0f / (1.0f + __expf(-x)); }
__device__ __forceinline__ float tanh_f(float x) { return 1.0f - 2.0f / (__expf(2.0f * x) + 1.0f); }

// 16B device-coherent load (2x 8B relaxed agent atomics -> sc1 bypass to LLC)
__device__ __forceinline__ bf16x8 ld16_dev(const bf16_t* p) {
    const unsigned long long* q = (const unsigned long long*)p;
    unsigned long long v0 = __hip_atomic_load(q, __ATOMIC_RELAXED, SCOPE_DEV);
    unsigned long long v1 = __hip_atomic_load(q + 1, __ATOMIC_RELAXED, SCOPE_DEV);
    union { unsigned long long u[2]; bf16x8 v; } c;
    c.u[0] = v0; c.u[1] = v1;
    return c.v;
}
// 8B device-coherent store (write-through to LLC)
__device__ __forceinline__ void st8_dev(bf16_t* p, unsigned long long v) {
    __hip_atomic_store((unsigned long long*)p, v, __ATOMIC_RELAXED, SCOPE_DEV);
}

// ---------------- prep: fp32->bf16 conversions + bias sums ----------------
__global__ void prep_kernel(const float* __restrict__ c_star, const float* __restrict__ ihw,
                            const float* __restrict__ icw, const float* __restrict__ whh0,
                            const float* __restrict__ whh1, const float* __restrict__ bi0,
                            const float* __restrict__ bh0, const float* __restrict__ bi1,
                            const float* __restrict__ bh1,
                            bf16_t* __restrict__ csb, bf16_t* __restrict__ ihwb,
                            bf16_t* __restrict__ icwb, bf16_t* __restrict__ whh0b,
                            bf16_t* __restrict__ whh1b, float* __restrict__ gb0,
                            float* __restrict__ gb1) {
    int id = blockIdx.x * TPB + threadIdx.x;
    if (id < 262144) { csb[id] = (bf16_t)c_star[id]; return; }
    id -= 262144;
    if (id < 524288) { ihwb[id] = (bf16_t)ihw[id]; return; }
    id -= 524288;
    if (id < 524288) { icwb[id] = (bf16_t)icw[id]; return; }
    id -= 524288;
    if (id < 1048576) { whh0b[id] = (bf16_t)whh0[id]; return; }
    id -= 1048576;
    if (id < 1048576) { whh1b[id] = (bf16_t)whh1[id]; return; }
    id -= 1048576;
    if (id < 2048) { gb0[id] = bi0[id] + bh0[id]; return; }
    id -= 2048;
    if (id < 2048) { gb1[id] = bi1[id] + bh1[id]; return; }
}

// ---------------- pack W_ih1 into MFMA B-fragment order ----------------
__global__ void pack_wih1_kernel(const float* __restrict__ W, bf16_t* __restrict__ out) {
    int id = blockIdx.x * TPB + threadIdx.x;  // 131072 chunks
    int j = id >> 13;
    int ch = id & 8191;
    int c = ch >> 6;             // 0..127 local col
    int k0 = (ch & 63) << 3;     // 0..511 step 8
    int q = c >> 5, dd = c & 31;
    int src = (q * 512 + j * 32 + dd) * 512 + k0;
    int kt = k0 >> 4, hi = (k0 >> 3) & 1;
    int off = (j * 4 + q) * 16384 + kt * 512 + ((hi << 5) + dd) * 8;
#pragma unroll
    for (int jj = 0; jj < 8; jj++) out[off + jj] = (bf16_t)W[src + jj];
}

// ---------------- init GEMM: h0/c0 = tanh(c_star @ W.T + b) ----------------
__global__ __launch_bounds__(TPB) void init_gemm_kernel(
    const bf16_t* __restrict__ csb, const bf16_t* __restrict__ ihwb,
    const bf16_t* __restrict__ icwb, const float* __restrict__ ihb,
    const float* __restrict__ icb, bf16_t* __restrict__ hl0, bf16_t* __restrict__ hl1,
    float* __restrict__ cl0, float* __restrict__ cl1) {
    int bid = blockIdx.x;
    int mt = bid & 15, nt = bid >> 4;
    int tid = threadIdx.x;
    int w = tid >> 6, l = tid & 63;
    int lane32 = l & 31, lhi = l >> 5;
    int m0 = mt * 32;
    int n0 = nt * 128 + w * 32;  // 0..2047
    bool is_h = (n0 < 1024);
    const bf16_t* Bmat = is_h ? ihwb : icwb;
    const float* bias = is_h ? ihb : icb;
    int nloc = is_h ? n0 : (n0 - 1024);

    f32x16 acc = {};
    const bf16_t* ap = csb + (m0 + lane32) * 512 + lhi * 8;
    const bf16_t* bp = Bmat + (nloc + lane32) * 512 + lhi * 8;
#pragma unroll
    for (int kt = 0; kt < 32; kt++) {
        bf16x8 a = *(const bf16x8*)(ap + kt * 16);
        bf16x8 b = *(const bf16x8*)(bp + kt * 16);
        acc = __builtin_amdgcn_mfma_f32_32x32x16_bf16(a, b, acc, 0, 0, 0);
    }
    int n = nloc + lane32;
    float bv = bias[n];
#pragma unroll
    for (int reg = 0; reg < 16; reg++) {
        int row = (reg & 3) + ((reg >> 2) << 3) + (lhi << 2);
        int m = m0 + row;
        float v = tanh_f(acc[reg] + bv);
        int flat = m * 1024 + n;  // reshape(NL,B,D) flat split semantics
        if (is_h) {
            if (flat < 262144) hl0[flat] = (bf16_t)v;
            else hl1[flat - 262144] = (bf16_t)v;
        } else {
            if (flat < 262144) cl0[flat] = v;
            else cl1[flat - 262144] = v;
        }
    }
}

// ---------------- main persistent cooperative LSTM kernel ----------------
__global__ __launch_bounds__(TPB, 1) void lstm_main_kernel(
    const bf16_t* __restrict__ whh0, const bf16_t* __restrict__ whh1,
    const bf16_t* __restrict__ wih1p, const float* __restrict__ gb0,
    const float* __restrict__ gb1, const float* __restrict__ out_w,
    bf16_t* __restrict__ hl0, bf16_t* __restrict__ hl1,
    const float* __restrict__ cl0i, const float* __restrict__ cl1i,
    bf16_t* __restrict__ y0, float* __restrict__ OP, unsigned* __restrict__ ctr) {
    __shared__ __align__(16) char smem[149504];  // 128KB W frags + 16KB gates + 2KB Hs
    bf16_t* Wlds = (bf16_t*)smem;
    float* G = (float*)(smem + 131072);
    bf16_t* Hs = (bf16_t*)(smem + 147456);  // 32 rows x 32 cols bf16

    const int bid = blockIdx.x;
    const int r8 = bid & 7, k8 = bid >> 3;
    const int g = r8 + ((k8 >> 4) << 3);  // group 0..15 (same-XCD hint)
    const int j = k8 & 15;                // d-slice within group
    const int b0 = g * 32, d0 = j * 32;
    const int tid = threadIdx.x;
    const int w = tid >> 6, l = tid & 63;
    const int lane32 = l & 31, lhi = l >> 5;
    const int ec = tid & 31, er = tid >> 5;  // elementwise (col, row-base)
    const int prow = tid >> 3, pc4 = (tid & 7) << 2;  // pack (row, col4)
    unsigned* myctr = ctr + g * 64;  // 256B stripe per group: no same-line contention

    // stage W_hh0 into frag-major LDS (input written by prior kernel: plain loads ok)
    for (int ch = tid; ch < 8192; ch += TPB) {
        int c = ch >> 6, k0 = (ch & 63) << 3;
        int q = c >> 5, dd = c & 31;
        bf16x8 v = *(const bf16x8*)(whh0 + (q * 512 + d0 + dd) * 512 + k0);
        *(bf16x8*)(Wlds + q * 16384 + (k0 >> 4) * 512 + ((((k0 >> 3) & 1) << 5) + dd) * 8) = v;
    }
    __syncthreads();

    float cst[4], bq[4];
#pragma unroll
    for (int p = 0; p < 4; p++) cst[p] = cl0i[(b0 + p * 8 + er) * 512 + d0 + ec];
#pragma unroll
    for (int q = 0; q < 4; q++) bq[q] = gb0[q * 512 + d0 + ec];

    int barcnt = 0;

    // ================= Phase A: layer 0 (input is bias-only) =================
    for (int t = 0; t < 256; t++) {
        const bf16_t* hcur = hl0 + (t & 1) * 262144;
        bf16_t* hnxt = hl0 + ((t + 1) & 1) * 262144;
        f32x16 acc = {};
        const bf16_t* ap = hcur + (b0 + lane32) * 512 + lhi * 8;
        const bf16_t* bp = Wlds + w * 16384 + l * 8;
#pragma unroll
        for (int kt = 0; kt < 32; kt++) {
            bf16x8 a = ld16_dev(ap + kt * 16);
            bf16x8 b = *(const bf16x8*)(bp + kt * 512);
            acc = __builtin_amdgcn_mfma_f32_32x32x16_bf16(a, b, acc, 0, 0, 0);
        }
#pragma unroll
        for (int reg = 0; reg < 16; reg++) {
            int row = (reg & 3) + ((reg >> 2) << 3) + (lhi << 2);
            G[w * 1024 + row * 32 + lane32] = acc[reg];
        }
        __syncthreads();
#pragma unroll
        for (int p = 0; p < 4; p++) {
            int r = p * 8 + er;
            float iv = sigm(G[r * 32 + ec] + bq[0]);
            float fv = sigm(G[1024 + r * 32 + ec] + bq[1]);
            float gv = tanh_f(G[2048 + r * 32 + ec] + bq[2]);
            float ov = sigm(G[3072 + r * 32 + ec] + bq[3]);
            float cv = fv * cst[p] + iv * gv;
            cst[p] = cv;
            Hs[r * 32 + ec] = (bf16_t)(ov * tanh_f(cv));
        }
        __syncthreads();
        // pack 8B chunks, write-through to LLC (h for siblings, y0 for phase B)
        {
            unsigned long long v = *(const unsigned long long*)(Hs + prow * 32 + pc4);
            int gi = (b0 + prow) * 512 + d0 + pc4;
            st8_dev(hnxt + gi, v);
            st8_dev(y0 + t * 262144 + gi, v);
        }
        asm volatile("s_waitcnt vmcnt(0)" ::: "memory");
        __syncthreads();
        barcnt++;
        if (tid == 0) {
            __hip_atomic_fetch_add(myctr, 1u, __ATOMIC_RELAXED, SCOPE_DEV);
            unsigned tgt = (unsigned)(16 * barcnt);
            while (__hip_atomic_load(myctr, __ATOMIC_RELAXED, SCOPE_DEV) < tgt)
                __builtin_amdgcn_s_sleep(2);
        }
        __syncthreads();
    }

    // stage W_hh1 (all waves past GEMM reads due to final barrier)
    for (int ch = tid; ch < 8192; ch += TPB) {
        int c = ch >> 6, k0 = (ch & 63) << 3;
        int q = c >> 5, dd = c & 31;
        bf16x8 v = *(const bf16x8*)(whh1 + (q * 512 + d0 + dd) * 512 + k0);
        *(bf16x8*)(Wlds + q * 16384 + (k0 >> 4) * 512 + ((((k0 >> 3) & 1) << 5) + dd) * 8) = v;
    }
    __syncthreads();
#pragma unroll
    for (int p = 0; p < 4; p++) cst[p] = cl1i[(b0 + p * 8 + er) * 512 + d0 + ec];
#pragma unroll
    for (int q = 0; q < 4; q++) bq[q] = gb1[q * 512 + d0 + ec];
    const float ow = out_w[d0 + ec];
    const bf16_t* wp = wih1p + (j * 4 + w) * 16384 + l * 8;
    float* opj = OP + j * 131072;  // this block's private O-partial slice

    // ================= Phase B: layer 1 (K=1024 fused) + out proj ============
    for (int t = 0; t < 256; t++) {
        const bf16_t* hcur = hl1 + (t & 1) * 262144;
        bf16_t* hnxt = hl1 + ((t + 1) & 1) * 262144;
        f32x16 acc = {};
        // y-GEMM: y0[t] is immutable since Phase A and first-read this launch
        // -> PLAIN CACHED loads; compiler pipelines them (unordered), counted
        // waits safe; hoisting above the barrier poll is harmless.
        {
            const bf16_t* yp = y0 + t * 262144 + (b0 + lane32) * 512 + lhi * 8;
#pragma unroll
            for (int kt = 0; kt < 32; kt++) {
                bf16x8 a = *(const bf16x8*)(yp + kt * 16);
                acc = __builtin_amdgcn_mfma_f32_32x32x16_bf16(a, *(const bf16x8*)(wp + kt * 512), acc, 0, 0, 0);
            }
        }
        // h-GEMM: cross-block fresh data each step -> coherent serialized path
        // (proven correct; burst variants all failed)
        {
            const bf16_t* ap = hcur + (b0 + lane32) * 512 + lhi * 8;
            const bf16_t* bp = Wlds + w * 16384 + l * 8;
#pragma unroll
            for (int kt = 0; kt < 32; kt++) {
                bf16x8 a = ld16_dev(ap + kt * 16);
                bf16x8 b = *(const bf16x8*)(bp + kt * 512);
                acc = __builtin_amdgcn_mfma_f32_32x32x16_bf16(a, b, acc, 0, 0, 0);
            }
        }
#pragma unroll
        for (int reg = 0; reg < 16; reg++) {
            int row = (reg & 3) + ((reg >> 2) << 3) + (lhi << 2);
            G[w * 1024 + row * 32 + lane32] = acc[reg];
        }
        __syncthreads();
#pragma unroll
        for (int p = 0; p < 4; p++) {
            int r = p * 8 + er;
            float iv = sigm(G[r * 32 + ec] + bq[0]);
            float fv = sigm(G[1024 + r * 32 + ec] + bq[1]);
            float gv = tanh_f(G[2048 + r * 32 + ec] + bq[2]);
            float ov = sigm(G[3072 + r * 32 + ec] + bq[3]);
            float cv = fv * cst[p] + iv * gv;
            cst[p] = cv;
            float hv = ov * tanh_f(cv);
            Hs[r * 32 + ec] = (bf16_t)hv;
            float part = hv * ow;
#pragma unroll
            for (int off = 16; off; off >>= 1) part += __shfl_xor(part, off, 32);
            if (ec == 0) opj[t * 512 + b0 + r] = part;  // contention-free partial
        }
        __syncthreads();
        {
            unsigned long long v = *(const unsigned long long*)(Hs + prow * 32 + pc4);
            st8_dev(hnxt + (b0 + prow) * 512 + d0 + pc4, v);
        }
        asm volatile("s_waitcnt vmcnt(0)" ::: "memory");
        __syncthreads();
        barcnt++;
        if (tid == 0) {
            __hip_atomic_fetch_add(myctr, 1u, __ATOMIC_RELAXED, SCOPE_DEV);
            unsigned tgt = (unsigned)(16 * barcnt);
            while (__hip_atomic_load(myctr, __ATOMIC_RELAXED, SCOPE_DEV) < tgt)
                __builtin_amdgcn_s_sleep(2);
        }
        __syncthreads();
    }
}

// ------------- finalize: 16-way O-partial reduce + out_b + reorder -------------
__global__ void finalize_kernel(const float* __restrict__ OP, const float* __restrict__ out_b,
                                float* __restrict__ out) {
    int id = blockIdx.x * TPB + threadIdx.x;  // 131072
    int t = id >> 9, b = id & 511;
    float v = out_b[0];
#pragma unroll
    for (int jj = 0; jj < 16; jj++) v += OP[jj * 131072 + id];
    if (t < 255) out[b * 255 + t] = v;
    else out[130560 + b] = v;
}

extern "C" void kernel_launch(void* const* d_in, const int* in_sizes, int n_in,
                              void* d_out, int out_size, void* d_ws, size_t ws_size,
                              hipStream_t stream) {
    const float* c_star = (const float*)d_in[0];
    const float* init_h_w = (const float*)d_in[1];
    const float* init_h_b = (const float*)d_in[2];
    const float* init_c_w = (const float*)d_in[3];
    const float* init_c_b = (const float*)d_in[4];
    // d_in[5] = W_ih0 (unused by reference)
    const float* W_hh0 = (const float*)d_in[6];
    const float* b_ih0 = (const float*)d_in[7];
    const float* b_hh0 = (const float*)d_in[8];
    const float* W_ih1 = (const float*)d_in[9];
    const float* W_hh1 = (const float*)d_in[10];
    const float* b_ih1 = (const float*)d_in[11];
    const float* b_hh1 = (const float*)d_in[12];
    const float* out_w = (const float*)d_in[13];
    const float* out_b = (const float*)d_in[14];

    char* ws = (char*)d_ws;
    unsigned* ctr = (unsigned*)(ws + OFF_CTR);
    bf16_t* hl0 = (bf16_t*)(ws + OFF_HL0);
    bf16_t* hl1 = (bf16_t*)(ws + OFF_HL1);
    float* cl0 = (float*)(ws + OFF_CL0);
    float* cl1 = (float*)(ws + OFF_CL1);
    bf16_t* csb = (bf16_t*)(ws + OFF_CSB);
    bf16_t* ihwb = (bf16_t*)(ws + OFF_IHWB);
    bf16_t* icwb = (bf16_t*)(ws + OFF_ICWB);
    bf16_t* whh0b = (bf16_t*)(ws + OFF_WHH0B);
    bf16_t* whh1b = (bf16_t*)(ws + OFF_WHH1B);
    bf16_t* wih1p = (bf16_t*)(ws + OFF_WIH1P);
    float* gb0 = (float*)(ws + OFF_GB0);
    float* gb1 = (float*)(ws + OFF_GB1);
    bf16_t* y0 = (bf16_t*)(ws + OFF_Y0);
    float* OP = (float*)(ws + OFF_OP);

    // zero group barrier counters (ws is poisoned each call); OP is fully
    // overwritten in Phase B before finalize reads it -> no zeroing needed
    hipMemsetAsync(ws + OFF_CTR, 0, 4096, stream);

    prep_kernel<<<13328, TPB, 0, stream>>>(c_star, init_h_w, init_c_w, W_hh0, W_hh1,
                                           b_ih0, b_hh0, b_ih1, b_hh1,
                                           csb, ihwb, icwb, whh0b, whh1b, gb0, gb1);
    pack_wih1_kernel<<<512, TPB, 0, stream>>>(W_ih1, wih1p);
    init_gemm_kernel<<<256, TPB, 0, stream>>>(csb, ihwb, icwb, init_h_b, init_c_b,
                                              hl0, hl1, cl0, cl1);

    const bf16_t* a_whh0 = whh0b; const bf16_t* a_whh1 = whh1b;
    const bf16_t* a_wih1p = wih1p; const float* a_gb0 = gb0; const float* a_gb1 = gb1;
    const float* a_outw = out_w;
    bf16_t* a_hl0 = hl0; bf16_t* a_hl1 = hl1;
    const float* a_cl0 = cl0; const float* a_cl1 = cl1;
    bf16_t* a_y0 = y0; float* a_OP = OP; unsigned* a_ctr = ctr;
    void* args[] = {&a_whh0, &a_whh1, &a_wih1p, &a_gb0, &a_gb1, &a_outw,
                    &a_hl0, &a_hl1, &a_cl0, &a_cl1, &a_y0, &a_OP, &a_ctr};
    hipLaunchCooperativeKernel((void*)lstm_main_kernel, dim3(NB), dim3(TPB), args, 0, stream);

    finalize_kernel<<<512, TPB, 0, stream>>>(OP, out_b, (float*)d_out);
}